// Round 1
// baseline (286.625 us; speedup 1.0000x reference)
//
#include <hip/hip_runtime.h>
#include <hip/hip_fp16.h>

typedef _Float16 f16;
typedef _Float16 f16x8 __attribute__((ext_vector_type(8)));
typedef _Float16 f16x4 __attribute__((ext_vector_type(4)));
typedef float    f32x4 __attribute__((ext_vector_type(4)));

#define DEV __device__ __forceinline__

static constexpr int Tn = 2048;      // sequence length
static constexpr int Dn = 1024;      // model dim
static constexpr int Hn = 16;        // heads
static constexpr int HDn = 64;       // head dim
static constexpr int Mn = 2 * Tn;    // 4096 rows (B*T)
static constexpr int NQKV = 3 * Dn;  // 3072

DEV void gld16(const void* g, void* l) {
  __builtin_amdgcn_global_load_lds((const __attribute__((address_space(1))) unsigned int*)g,
                                   (__attribute__((address_space(3))) unsigned int*)l, 16, 0, 0);
}

// ---------------- cast x (f32 -> f16) ----------------
__global__ __launch_bounds__(256) void k_cast_x(const float* __restrict__ x, f16* __restrict__ xb) {
  int i = blockIdx.x * 256 + threadIdx.x;            // i < Mn*Dn/4
  float4 v = ((const float4*)x)[i];
  f16x4 o; o.x = (f16)v.x; o.y = (f16)v.y; o.z = (f16)v.z; o.w = (f16)v.w;
  ((f16x4*)xb)[i] = o;
}

// ---------------- transpose+cast weights: dst[n][k] = w[k][n] ----------------
__global__ __launch_bounds__(256) void k_wtrans(const float* __restrict__ wq, const float* __restrict__ wk,
                                                const float* __restrict__ wv, const float* __restrict__ wo,
                                                f16* __restrict__ wcat_t, f16* __restrict__ wot) {
  __shared__ float tile[64][65];
  const float* srcs[4] = {wq, wk, wv, wo};
  const float* w = srcs[blockIdx.z];
  f16* dst = (blockIdx.z == 3) ? wot : wcat_t + (size_t)blockIdx.z * Dn * Dn;
  int k0 = blockIdx.x * 64, n0 = blockIdx.y * 64;
#pragma unroll
  for (int p = 0; p < 16; ++p) {
    int flat = threadIdx.x + p * 256;
    int kl = flat >> 6, nl = flat & 63;
    tile[kl][nl] = w[(size_t)(k0 + kl) * Dn + n0 + nl];
  }
  __syncthreads();
#pragma unroll
  for (int p = 0; p < 16; ++p) {
    int flat = threadIdx.x + p * 256;
    int nl = flat >> 6, kl = flat & 63;
    dst[(size_t)(n0 + nl) * Dn + k0 + kl] = (f16)tile[kl][nl];
  }
}

// ---------------- 128x128 tile GEMM: C[M x N] = A[M x K] * Bt[N x K]^T ----------------
// A, Bt f16; out f16 (flag) or f32. K multiple of 64. Grid: (N/128, M/128), 256 threads.
__global__ __launch_bounds__(256) void k_gemm(const f16* __restrict__ A, const f16* __restrict__ Bt,
                                              void* __restrict__ Cout, int N, int K, int out_f16) {
  __shared__ __align__(16) f16 As[128 * 64];
  __shared__ __align__(16) f16 Bs[128 * 64];
  const int lane = threadIdx.x & 63, wid = threadIdx.x >> 6;
  const int m0 = blockIdx.y * 128, n0 = blockIdx.x * 128;
  const int wr = (wid >> 1) * 64, wc = (wid & 1) * 64;
  f32x4 acc[4][4];
#pragma unroll
  for (int i = 0; i < 4; ++i)
#pragma unroll
    for (int j = 0; j < 4; ++j) acc[i][j] = (f32x4){0.f, 0.f, 0.f, 0.f};

  char* AsB = (char*)As; char* BsB = (char*)Bs;
  for (int k0 = 0; k0 < K; k0 += 64) {
    __syncthreads();
#pragma unroll
    for (int it = 0; it < 4; ++it) {
      int flat = ((wid * 4 + it) * 64 + lane) * 16;   // byte in 16KB tile
      int row = flat >> 7, g = (flat >> 4) & 7;
      int sw = (g ^ (row & 7)) << 4;
      gld16((const char*)A + ((size_t)(m0 + row) * K + k0) * 2 + sw, AsB + (wid * 4 + it) * 1024);
      gld16((const char*)Bt + ((size_t)(n0 + row) * K + k0) * 2 + sw, BsB + (wid * 4 + it) * 1024);
    }
    __syncthreads();
#pragma unroll
    for (int kk = 0; kk < 2; ++kk) {
      f16x8 af[4], bf[4];
#pragma unroll
      for (int ms = 0; ms < 4; ++ms) {
        int r = wr + ms * 16 + (lane & 15);
        af[ms] = *(const f16x8*)(AsB + r * 128 + (((kk * 4 + (lane >> 4)) ^ (r & 7)) << 4));
      }
#pragma unroll
      for (int ns = 0; ns < 4; ++ns) {
        int r = wc + ns * 16 + (lane & 15);
        bf[ns] = *(const f16x8*)(BsB + r * 128 + (((kk * 4 + (lane >> 4)) ^ (r & 7)) << 4));
      }
#pragma unroll
      for (int ms = 0; ms < 4; ++ms)
#pragma unroll
        for (int ns = 0; ns < 4; ++ns)
          acc[ms][ns] = __builtin_amdgcn_mfma_f32_16x16x32_f16(af[ms], bf[ns], acc[ms][ns], 0, 0, 0);
    }
  }
  const int rq = lane >> 4, cq = lane & 15;
  if (out_f16) {
    f16* C = (f16*)Cout;
#pragma unroll
    for (int ms = 0; ms < 4; ++ms)
#pragma unroll
      for (int ns = 0; ns < 4; ++ns)
#pragma unroll
        for (int r = 0; r < 4; ++r)
          C[(size_t)(m0 + wr + ms * 16 + rq * 4 + r) * N + n0 + wc + ns * 16 + cq] = (f16)acc[ms][ns][r];
  } else {
    float* C = (float*)Cout;
#pragma unroll
    for (int ms = 0; ms < 4; ++ms)
#pragma unroll
      for (int ns = 0; ns < 4; ++ns)
#pragma unroll
        for (int r = 0; r < 4; ++r)
          C[(size_t)(m0 + wr + ms * 16 + rq * 4 + r) * N + n0 + wc + ns * 16 + cq] = acc[ms][ns][r];
  }
}

// ---------------- per-row qk RMSNorm + head rearrange ----------------
// y[Mn][3072] f16 (cols: q | k | v, col c within section maps to (h=c&15, d=c>>4))
// outputs: qatt/katt/vatt [32 bh][T][64] f16. q gets *0.125 fold of attention scale.
__global__ __launch_bounds__(256) void k_norm(const f16* __restrict__ y, const float* __restrict__ qw,
                                              const float* __restrict__ kw, f16* __restrict__ qatt,
                                              f16* __restrict__ katt, f16* __restrict__ vatt) {
  __shared__ float lq[16][65], lk[16][65], lv[16][65];
  int tg = blockIdx.x;                 // 0..4095
  int b = tg >> 11, t = tg & 2047;
  const f16* row = y + (size_t)tg * NQKV;
  for (int c = threadIdx.x; c < NQKV; c += 256) {
    float v = (float)row[c];
    int sec = c >> 10, cs = c & 1023;
    float (*dst)[65] = (sec == 0) ? lq : (sec == 1) ? lk : lv;
    dst[cs & 15][cs >> 4] = v;
  }
  __syncthreads();
  int lane = threadIdx.x & 63, wid = threadIdx.x >> 6;
#pragma unroll
  for (int hh = 0; hh < 4; ++hh) {
    int h = wid * 4 + hh;
    float qv = lq[h][lane], kv = lk[h][lane], vv = lv[h][lane];
    float sq = qv * qv, sk = kv * kv;
#pragma unroll
    for (int msk = 1; msk < 64; msk <<= 1) {
      sq += __shfl_xor(sq, msk, 64);
      sk += __shfl_xor(sk, msk, 64);
    }
    float rq = rsqrtf(sq * (1.f / 64) + 1e-5f) * qw[lane] * 0.125f;
    float rk = rsqrtf(sk * (1.f / 64) + 1e-5f) * kw[lane];
    size_t obase = (((size_t)(b * 16 + h)) * Tn + t) * 64 + lane;
    qatt[obase] = (f16)(qv * rq);
    katt[obase] = (f16)(kv * rk);
    vatt[obase] = (f16)vv;
  }
}

// ---------------- V transpose: vt[bh][d][t] = vatt[bh][t][d] ----------------
__global__ __launch_bounds__(256) void k_vtrans(const f16* __restrict__ vatt, f16* __restrict__ vt) {
  __shared__ f16 tile[64][72];
  int t0 = blockIdx.x * 64, bh = blockIdx.y;
  const f16* src = vatt + ((size_t)bh * Tn + t0) * 64;
#pragma unroll
  for (int p = 0; p < 2; ++p) {
    int c = threadIdx.x + p * 256;     // 0..511
    int tl = c >> 3, dc = (c & 7) * 8;
    f16x8 v = *(const f16x8*)(src + (size_t)tl * 64 + dc);
#pragma unroll
    for (int j = 0; j < 8; ++j) tile[dc + j][tl] = v[j];
  }
  __syncthreads();
#pragma unroll
  for (int p = 0; p < 2; ++p) {
    int c = threadIdx.x + p * 256;
    int d = c >> 3, tc = (c & 7) * 8;
    f16x8 o;
#pragma unroll
    for (int j = 0; j < 8; ++j) o[j] = tile[d][tc + j];
    *(f16x8*)(vt + ((size_t)bh * 64 + d) * Tn + t0 + tc) = o;
  }
}

// ---------------- flash attention: 4 waves x 16 q-rows, KVBLK=64 ----------------
// qatt/katt [bh][T][64] (q pre-scaled), vt [bh][64][T]; out attout[b*T+t][h*64+d] f16
__global__ __launch_bounds__(256) void k_attn(const f16* __restrict__ qatt, const f16* __restrict__ katt,
                                              const f16* __restrict__ vt, f16* __restrict__ attout) {
  __shared__ __align__(16) f16 Ks[64 * 64];
  __shared__ __align__(16) f16 Vs[64 * 64];
  __shared__ __align__(16) f16 Ps[4][16 * 64];
  const int lane = threadIdx.x & 63, wid = threadIdx.x >> 6;
  const int bh = blockIdx.y, b = bh >> 4, h = bh & 15;
  const int tq0 = blockIdx.x * 64 + wid * 16;

  const f16* qbase = qatt + ((size_t)bh * Tn + tq0) * 64;
  f16x8 qf[2];
#pragma unroll
  for (int kk = 0; kk < 2; ++kk)
    qf[kk] = *(const f16x8*)(qbase + (size_t)(lane & 15) * 64 + kk * 32 + (lane >> 4) * 8);

  f32x4 o[4];
  float mreg[4], lsum[4];
#pragma unroll
  for (int i = 0; i < 4; ++i) { o[i] = (f32x4){0.f, 0.f, 0.f, 0.f}; mreg[i] = -1e30f; lsum[i] = 0.f; }

  const char* kgb = (const char*)(katt + (size_t)bh * Tn * 64);
  const char* vgb = (const char*)(vt + (size_t)bh * 64 * Tn);
  char* KsB = (char*)Ks; char* VsB = (char*)Vs; char* PsB = (char*)Ps[wid];

  for (int kt = 0; kt < Tn / 64; ++kt) {
    int k0 = kt * 64;
    __syncthreads();
#pragma unroll
    for (int it = 0; it < 2; ++it) {
      int flat = ((wid * 2 + it) * 64 + lane) * 16;
      int row = flat >> 7, g = (flat >> 4) & 7;
      int sw = (g ^ (row & 7)) << 4;
      gld16(kgb + ((size_t)(k0 + row) * 64) * 2 + sw, KsB + (wid * 2 + it) * 1024);
      gld16(vgb + ((size_t)row * Tn + k0) * 2 + sw, VsB + (wid * 2 + it) * 1024);
    }
    __syncthreads();

    // S = Q K^T  (16 x 64 per wave)
    f32x4 s[4];
#pragma unroll
    for (int sub = 0; sub < 4; ++sub) {
      s[sub] = (f32x4){0.f, 0.f, 0.f, 0.f};
#pragma unroll
      for (int kk = 0; kk < 2; ++kk) {
        int kr = sub * 16 + (lane & 15);
        f16x8 kf = *(const f16x8*)(KsB + kr * 128 + (((kk * 4 + (lane >> 4)) ^ (kr & 7)) << 4));
        s[sub] = __builtin_amdgcn_mfma_f32_16x16x32_f16(qf[kk], kf, s[sub], 0, 0, 0);
      }
    }

    // online softmax (f32). rows for this lane: (lane>>4)*4 + r
    float rmax[4];
#pragma unroll
    for (int r = 0; r < 4; ++r)
      rmax[r] = fmaxf(fmaxf(s[0][r], s[1][r]), fmaxf(s[2][r], s[3][r]));
#pragma unroll
    for (int msk = 1; msk < 16; msk <<= 1)
#pragma unroll
      for (int r = 0; r < 4; ++r) rmax[r] = fmaxf(rmax[r], __shfl_xor(rmax[r], msk, 64));
    float mn[4], al[4], rs[4];
#pragma unroll
    for (int r = 0; r < 4; ++r) {
      mn[r] = fmaxf(mreg[r], rmax[r]);
      al[r] = __expf(mreg[r] - mn[r]);
      mreg[r] = mn[r];
    }
#pragma unroll
    for (int sub = 0; sub < 4; ++sub)
#pragma unroll
      for (int r = 0; r < 4; ++r) s[sub][r] = __expf(s[sub][r] - mn[r]);
#pragma unroll
    for (int r = 0; r < 4; ++r) rs[r] = s[0][r] + s[1][r] + s[2][r] + s[3][r];
#pragma unroll
    for (int msk = 1; msk < 16; msk <<= 1)
#pragma unroll
      for (int r = 0; r < 4; ++r) rs[r] += __shfl_xor(rs[r], msk, 64);
#pragma unroll
    for (int r = 0; r < 4; ++r) lsum[r] = lsum[r] * al[r] + rs[r];
#pragma unroll
    for (int ds = 0; ds < 4; ++ds)
#pragma unroll
      for (int r = 0; r < 4; ++r) o[ds][r] *= al[r];

    // write P (f16) into per-wave swizzled LDS buffer
#pragma unroll
    for (int sub = 0; sub < 4; ++sub)
#pragma unroll
      for (int r = 0; r < 4; ++r) {
        int row = (lane >> 4) * 4 + r;
        int byte = row * 128 + ((((lane & 15) * 2 + sub * 32)) ^ ((row & 7) << 4));
        *(f16*)(PsB + byte) = (f16)s[sub][r];
      }

    // O += P V
    f16x8 pa[2];
#pragma unroll
    for (int kk = 0; kk < 2; ++kk) {
      int row = lane & 15;
      pa[kk] = *(const f16x8*)(PsB + row * 128 + (((kk * 4 + (lane >> 4)) ^ (row & 7)) << 4));
    }
#pragma unroll
    for (int ds = 0; ds < 4; ++ds)
#pragma unroll
      for (int kk = 0; kk < 2; ++kk) {
        int dr = ds * 16 + (lane & 15);
        f16x8 vb = *(const f16x8*)(VsB + dr * 128 + (((kk * 4 + (lane >> 4)) ^ (dr & 7)) << 4));
        o[ds] = __builtin_amdgcn_mfma_f32_16x16x32_f16(pa[kk], vb, o[ds], 0, 0, 0);
      }
  }

  // epilogue: divide by l, write attout[b*T + t][h*64 + d]
  float inv[4];
#pragma unroll
  for (int r = 0; r < 4; ++r) inv[r] = 1.f / lsum[r];
#pragma unroll
  for (int ds = 0; ds < 4; ++ds)
#pragma unroll
    for (int r = 0; r < 4; ++r) {
      int t = tq0 + (lane >> 4) * 4 + r;
      attout[((size_t)(b * Tn + t)) * Dn + h * 64 + ds * 16 + (lane & 15)] = (f16)(o[ds][r] * inv[r]);
    }
}

// ---------------- host launch ----------------
extern "C" void kernel_launch(void* const* d_in, const int* in_sizes, int n_in,
                              void* d_out, int out_size, void* d_ws, size_t ws_size,
                              hipStream_t stream) {
  const float* x  = (const float*)d_in[0];
  const float* wq = (const float*)d_in[1];
  const float* wk = (const float*)d_in[2];
  const float* wv = (const float*)d_in[3];
  const float* wo = (const float*)d_in[4];
  const float* qw = (const float*)d_in[5];
  const float* kw = (const float*)d_in[6];

  char* ws = (char*)d_ws;
  const size_t MB = 1 << 20;
  f16* xb     = (f16*)(ws + 0 * MB);    // 8 MB
  f16* wcat   = (f16*)(ws + 8 * MB);    // 6 MB  [3072][1024] = W^T for q|k|v
  f16* wot    = (f16*)(ws + 14 * MB);   // 2 MB  [1024][1024] = Wo^T
  f16* y      = (f16*)(ws + 16 * MB);   // 24 MB [4096][3072]
  f16* qatt   = (f16*)(ws + 40 * MB);   // 8 MB  [32][2048][64]
  f16* katt   = (f16*)(ws + 48 * MB);   // 8 MB
  f16* vatt   = (f16*)(ws + 56 * MB);   // 8 MB
  f16* vtb    = (f16*)(ws + 64 * MB);   // 8 MB  [32][64][2048]
  f16* attout = (f16*)(ws + 72 * MB);   // 8 MB  [4096][1024]

  k_cast_x<<<dim3(Mn * Dn / 4 / 256), 256, 0, stream>>>(x, xb);
  k_wtrans<<<dim3(16, 16, 4), 256, 0, stream>>>(wq, wk, wv, wo, wcat, wot);
  k_gemm<<<dim3(NQKV / 128, Mn / 128), 256, 0, stream>>>(xb, wcat, (void*)y, NQKV, Dn, 1);
  k_norm<<<dim3(Mn), 256, 0, stream>>>(y, qw, kw, qatt, katt, vatt);
  k_vtrans<<<dim3(Tn / 64, 32), 256, 0, stream>>>(vatt, vtb);
  k_attn<<<dim3(Tn / 64, 32), 256, 0, stream>>>(qatt, katt, vtb, attout);
  k_gemm<<<dim3(Dn / 128, Mn / 128), 256, 0, stream>>>(attout, wot, d_out, Dn, Dn, 0);
}

// Round 2
// 239.095 us; speedup vs baseline: 1.1988x; 1.1988x over previous
//
#include <hip/hip_runtime.h>
#include <hip/hip_fp16.h>

typedef _Float16 f16;
typedef _Float16 f16x8 __attribute__((ext_vector_type(8)));
typedef _Float16 f16x4 __attribute__((ext_vector_type(4)));
typedef float    f32x4 __attribute__((ext_vector_type(4)));

#define DEV __device__ __forceinline__

static constexpr int Tn = 2048;      // sequence length
static constexpr int Dn = 1024;      // model dim
static constexpr int Hn = 16;        // heads
static constexpr int HDn = 64;       // head dim
static constexpr int Mn = 2 * Tn;    // 4096 rows (B*T)
static constexpr int NQKV = 3 * Dn;  // 3072

DEV void gld16(const void* g, void* l) {
  __builtin_amdgcn_global_load_lds((const __attribute__((address_space(1))) unsigned int*)g,
                                   (__attribute__((address_space(3))) unsigned int*)l, 16, 0, 0);
}

// ---------------- cast x (f32 -> f16) ----------------
__global__ __launch_bounds__(256) void k_cast_x(const float* __restrict__ x, f16* __restrict__ xb) {
  int i = blockIdx.x * 256 + threadIdx.x;            // i < Mn*Dn/4
  float4 v = ((const float4*)x)[i];
  f16x4 o; o.x = (f16)v.x; o.y = (f16)v.y; o.z = (f16)v.z; o.w = (f16)v.w;
  ((f16x4*)xb)[i] = o;
}

// ---------------- transpose+cast weights: dst[n][k] = w[k][n] ----------------
__global__ __launch_bounds__(256) void k_wtrans(const float* __restrict__ wq, const float* __restrict__ wk,
                                                const float* __restrict__ wv, const float* __restrict__ wo,
                                                f16* __restrict__ wcat_t, f16* __restrict__ wot) {
  __shared__ float tile[64][65];
  const float* srcs[4] = {wq, wk, wv, wo};
  const float* w = srcs[blockIdx.z];
  f16* dst = (blockIdx.z == 3) ? wot : wcat_t + (size_t)blockIdx.z * Dn * Dn;
  int k0 = blockIdx.x * 64, n0 = blockIdx.y * 64;
#pragma unroll
  for (int p = 0; p < 16; ++p) {
    int flat = threadIdx.x + p * 256;
    int kl = flat >> 6, nl = flat & 63;
    tile[kl][nl] = w[(size_t)(k0 + kl) * Dn + n0 + nl];
  }
  __syncthreads();
#pragma unroll
  for (int p = 0; p < 16; ++p) {
    int flat = threadIdx.x + p * 256;
    int nl = flat >> 6, kl = flat & 63;
    dst[(size_t)(n0 + nl) * Dn + k0 + kl] = (f16)tile[kl][nl];
  }
}

// ---------------- 128x128 tile GEMM: C[M x N] = A[M x K] * Bt[N x K]^T ----------------
// A, Bt f16; out f16 (flag) or f32. K multiple of 64. Grid: (N/128, M/128), 256 threads.
__global__ __launch_bounds__(256) void k_gemm(const f16* __restrict__ A, const f16* __restrict__ Bt,
                                              void* __restrict__ Cout, int N, int K, int out_f16) {
  __shared__ __align__(16) f16 As[128 * 64];
  __shared__ __align__(16) f16 Bs[128 * 64];
  const int lane = threadIdx.x & 63, wid = threadIdx.x >> 6;
  const int m0 = blockIdx.y * 128, n0 = blockIdx.x * 128;
  const int wr = (wid >> 1) * 64, wc = (wid & 1) * 64;
  f32x4 acc[4][4];
#pragma unroll
  for (int i = 0; i < 4; ++i)
#pragma unroll
    for (int j = 0; j < 4; ++j) acc[i][j] = (f32x4){0.f, 0.f, 0.f, 0.f};

  char* AsB = (char*)As; char* BsB = (char*)Bs;
  for (int k0 = 0; k0 < K; k0 += 64) {
    __syncthreads();
#pragma unroll
    for (int it = 0; it < 4; ++it) {
      int flat = ((wid * 4 + it) * 64 + lane) * 16;   // byte in 16KB tile
      int row = flat >> 7, g = (flat >> 4) & 7;
      int sw = (g ^ (row & 7)) << 4;
      gld16((const char*)A + ((size_t)(m0 + row) * K + k0) * 2 + sw, AsB + (wid * 4 + it) * 1024);
      gld16((const char*)Bt + ((size_t)(n0 + row) * K + k0) * 2 + sw, BsB + (wid * 4 + it) * 1024);
    }
    __syncthreads();
#pragma unroll
    for (int kk = 0; kk < 2; ++kk) {
      f16x8 af[4], bf[4];
#pragma unroll
      for (int ms = 0; ms < 4; ++ms) {
        int r = wr + ms * 16 + (lane & 15);
        af[ms] = *(const f16x8*)(AsB + r * 128 + (((kk * 4 + (lane >> 4)) ^ (r & 7)) << 4));
      }
#pragma unroll
      for (int ns = 0; ns < 4; ++ns) {
        int r = wc + ns * 16 + (lane & 15);
        bf[ns] = *(const f16x8*)(BsB + r * 128 + (((kk * 4 + (lane >> 4)) ^ (r & 7)) << 4));
      }
#pragma unroll
      for (int ms = 0; ms < 4; ++ms)
#pragma unroll
        for (int ns = 0; ns < 4; ++ns)
          acc[ms][ns] = __builtin_amdgcn_mfma_f32_16x16x32_f16(af[ms], bf[ns], acc[ms][ns], 0, 0, 0);
    }
  }
  const int rq = lane >> 4, cq = lane & 15;
  if (out_f16) {
    f16* C = (f16*)Cout;
#pragma unroll
    for (int ms = 0; ms < 4; ++ms)
#pragma unroll
      for (int ns = 0; ns < 4; ++ns)
#pragma unroll
        for (int r = 0; r < 4; ++r)
          C[(size_t)(m0 + wr + ms * 16 + rq * 4 + r) * N + n0 + wc + ns * 16 + cq] = (f16)acc[ms][ns][r];
  } else {
    float* C = (float*)Cout;
#pragma unroll
    for (int ms = 0; ms < 4; ++ms)
#pragma unroll
      for (int ns = 0; ns < 4; ++ns)
#pragma unroll
        for (int r = 0; r < 4; ++r)
          C[(size_t)(m0 + wr + ms * 16 + rq * 4 + r) * N + n0 + wc + ns * 16 + cq] = acc[ms][ns][r];
  }
}

// ---------------- per-row qk RMSNorm + head rearrange ----------------
// y[Mn][3072] f16 (cols: q | k | v, col c within section maps to (h=c&15, d=c>>4))
// outputs: qatt/katt/vatt [32 bh][T][64] f16.
// q gets *0.125*log2(e) fold (attention scale + exp2 base conversion).
__global__ __launch_bounds__(256) void k_norm(const f16* __restrict__ y, const float* __restrict__ qw,
                                              const float* __restrict__ kw, f16* __restrict__ qatt,
                                              f16* __restrict__ katt, f16* __restrict__ vatt) {
  __shared__ float lq[16][65], lk[16][65], lv[16][65];
  int tg = blockIdx.x;                 // 0..4095
  int b = tg >> 11, t = tg & 2047;
  const f16* row = y + (size_t)tg * NQKV;
  for (int c = threadIdx.x; c < NQKV; c += 256) {
    float v = (float)row[c];
    int sec = c >> 10, cs = c & 1023;
    float (*dst)[65] = (sec == 0) ? lq : (sec == 1) ? lk : lv;
    dst[cs & 15][cs >> 4] = v;
  }
  __syncthreads();
  int lane = threadIdx.x & 63, wid = threadIdx.x >> 6;
#pragma unroll
  for (int hh = 0; hh < 4; ++hh) {
    int h = wid * 4 + hh;
    float qv = lq[h][lane], kv = lk[h][lane], vv = lv[h][lane];
    float sq = qv * qv, sk = kv * kv;
#pragma unroll
    for (int msk = 1; msk < 64; msk <<= 1) {
      sq += __shfl_xor(sq, msk, 64);
      sk += __shfl_xor(sk, msk, 64);
    }
    // 0.125 (1/sqrt(64)) * log2(e) folded into q so scores are in log2 domain
    float rq = rsqrtf(sq * (1.f / 64) + 1e-5f) * qw[lane] * 0.1803368801111601f;
    float rk = rsqrtf(sk * (1.f / 64) + 1e-5f) * kw[lane];
    size_t obase = (((size_t)(b * 16 + h)) * Tn + t) * 64 + lane;
    qatt[obase] = (f16)(qv * rq);
    katt[obase] = (f16)(kv * rk);
    vatt[obase] = (f16)vv;
  }
}

// ---------------- V transpose: vt[bh][d][t] = vatt[bh][t][d] ----------------
__global__ __launch_bounds__(256) void k_vtrans(const f16* __restrict__ vatt, f16* __restrict__ vt) {
  __shared__ f16 tile[64][72];
  int t0 = blockIdx.x * 64, bh = blockIdx.y;
  const f16* src = vatt + ((size_t)bh * Tn + t0) * 64;
#pragma unroll
  for (int p = 0; p < 2; ++p) {
    int c = threadIdx.x + p * 256;     // 0..511
    int tl = c >> 3, dc = (c & 7) * 8;
    f16x8 v = *(const f16x8*)(src + (size_t)tl * 64 + dc);
#pragma unroll
    for (int j = 0; j < 8; ++j) tile[dc + j][tl] = v[j];
  }
  __syncthreads();
#pragma unroll
  for (int p = 0; p < 2; ++p) {
    int c = threadIdx.x + p * 256;
    int d = c >> 3, tc = (c & 7) * 8;
    f16x8 o;
#pragma unroll
    for (int j = 0; j < 8; ++j) o[j] = tile[d][tc + j];
    *(f16x8*)(vt + ((size_t)bh * 64 + d) * Tn + t0 + tc) = o;
  }
}

// ---------------- flash attention: 4 waves x 16 q-rows, KVBLK=64 ----------------
// No-max softmax: |S_log2| <= 8*log2(e) ~ 11.5 guaranteed by RMSNorm Cauchy-Schwarz,
// so P = exp2(S) <= 2981 fits f16; row-sum deferred entirely to epilogue.
// Double-buffered K/V staging with counted vmcnt (prefetch stays in flight across barriers).
// qatt/katt [bh][T][64] (q pre-scaled by 0.125*log2e), vt [bh][64][T]; out attout[b*T+t][h*64+d]
__global__ __launch_bounds__(256) void k_attn(const f16* __restrict__ qatt, const f16* __restrict__ katt,
                                              const f16* __restrict__ vt, f16* __restrict__ attout) {
  __shared__ __align__(16) f16 Ks[2][64 * 64];
  __shared__ __align__(16) f16 Vs[2][64 * 64];
  __shared__ __align__(16) f16 Ps[4][16 * 64];
  const int lane = threadIdx.x & 63, wid = threadIdx.x >> 6;
  const int bh = blockIdx.y, b = bh >> 4, h = bh & 15;
  const int tq0 = blockIdx.x * 64 + wid * 16;

  const f16* qbase = qatt + ((size_t)bh * Tn + tq0) * 64;
  f16x8 qf[2];
#pragma unroll
  for (int kk = 0; kk < 2; ++kk)
    qf[kk] = *(const f16x8*)(qbase + (size_t)(lane & 15) * 64 + kk * 32 + (lane >> 4) * 8);

  f32x4 o[4];
  float psum[4];
#pragma unroll
  for (int i = 0; i < 4; ++i) { o[i] = (f32x4){0.f, 0.f, 0.f, 0.f}; psum[i] = 0.f; }

  const char* kgb = (const char*)(katt + (size_t)bh * Tn * 64);
  const char* vgb = (const char*)(vt + (size_t)bh * 64 * Tn);
  char* KsB = (char*)Ks; char* VsB = (char*)Vs; char* PsB = (char*)Ps[wid];

  // per-wave staging: 2 gld16 for K + 2 for V = 4 outstanding VMEM ops per tile
  auto stage = [&](int buf, int kt) {
    int k0 = kt * 64;
#pragma unroll
    for (int it = 0; it < 2; ++it) {
      int flat = ((wid * 2 + it) * 64 + lane) * 16;
      int row = flat >> 7, g = (flat >> 4) & 7;
      int sw = (g ^ (row & 7)) << 4;
      gld16(kgb + ((size_t)(k0 + row) * 64) * 2 + sw, KsB + buf * 8192 + (wid * 2 + it) * 1024);
      gld16(vgb + ((size_t)row * Tn + k0) * 2 + sw, VsB + buf * 8192 + (wid * 2 + it) * 1024);
    }
  };

  constexpr int NT = Tn / 64;
  stage(0, 0);

  for (int kt = 0; kt < NT; ++kt) {
    const int cur = kt & 1;
    char* Kc = KsB + cur * 8192;
    char* Vc = VsB + cur * 8192;
    if (kt + 1 < NT) {
      stage(cur ^ 1, kt + 1);
      asm volatile("s_waitcnt vmcnt(4)" ::: "memory");   // cur's 4 loads done; next's stay in flight
    } else {
      asm volatile("s_waitcnt vmcnt(0)" ::: "memory");
    }
    __builtin_amdgcn_s_barrier();
    __builtin_amdgcn_sched_barrier(0);

    // S = Q K^T  (16 x 64 per wave), scores already in log2 domain
    f32x4 s[4];
    __builtin_amdgcn_s_setprio(1);
#pragma unroll
    for (int sub = 0; sub < 4; ++sub) {
      s[sub] = (f32x4){0.f, 0.f, 0.f, 0.f};
#pragma unroll
      for (int kk = 0; kk < 2; ++kk) {
        int kr = sub * 16 + (lane & 15);
        f16x8 kf = *(const f16x8*)(Kc + kr * 128 + (((kk * 4 + (lane >> 4)) ^ (kr & 7)) << 4));
        s[sub] = __builtin_amdgcn_mfma_f32_16x16x32_f16(qf[kk], kf, s[sub], 0, 0, 0);
      }
    }
    __builtin_amdgcn_s_setprio(0);

    // P = exp2(S); per-lane partial row-sums only (no cross-lane work in loop)
#pragma unroll
    for (int sub = 0; sub < 4; ++sub)
#pragma unroll
      for (int r = 0; r < 4; ++r) {
        float e = __builtin_amdgcn_exp2f(s[sub][r]);
        psum[r] += e;
        int row = (lane >> 4) * 4 + r;
        int byte = row * 128 + ((((lane & 15) * 2 + sub * 32)) ^ ((row & 7) << 4));
        *(f16*)(PsB + byte) = (f16)e;
      }

    // O += P V  (accumulate, no rescale ever)
    f16x8 pa[2];
#pragma unroll
    for (int kk = 0; kk < 2; ++kk) {
      int row = lane & 15;
      pa[kk] = *(const f16x8*)(PsB + row * 128 + (((kk * 4 + (lane >> 4)) ^ (row & 7)) << 4));
    }
    __builtin_amdgcn_s_setprio(1);
#pragma unroll
    for (int ds = 0; ds < 4; ++ds)
#pragma unroll
      for (int kk = 0; kk < 2; ++kk) {
        int dr = ds * 16 + (lane & 15);
        f16x8 vb = *(const f16x8*)(Vc + dr * 128 + (((kk * 4 + (lane >> 4)) ^ (dr & 7)) << 4));
        o[ds] = __builtin_amdgcn_mfma_f32_16x16x32_f16(pa[kk], vb, o[ds], 0, 0, 0);
      }
    __builtin_amdgcn_s_setprio(0);
    __builtin_amdgcn_s_barrier();   // all waves done with buf[cur] before it is restaged
  }

  // epilogue: one cross-lane row-sum reduce (over the 16 lanes sharing each row), divide, write
#pragma unroll
  for (int msk = 1; msk < 16; msk <<= 1)
#pragma unroll
    for (int r = 0; r < 4; ++r) psum[r] += __shfl_xor(psum[r], msk, 64);
  float inv[4];
#pragma unroll
  for (int r = 0; r < 4; ++r) inv[r] = 1.f / psum[r];
#pragma unroll
  for (int ds = 0; ds < 4; ++ds)
#pragma unroll
    for (int r = 0; r < 4; ++r) {
      int t = tq0 + (lane >> 4) * 4 + r;
      attout[((size_t)(b * Tn + t)) * Dn + h * 64 + ds * 16 + (lane & 15)] = (f16)(o[ds][r] * inv[r]);
    }
}

// ---------------- host launch ----------------
extern "C" void kernel_launch(void* const* d_in, const int* in_sizes, int n_in,
                              void* d_out, int out_size, void* d_ws, size_t ws_size,
                              hipStream_t stream) {
  const float* x  = (const float*)d_in[0];
  const float* wq = (const float*)d_in[1];
  const float* wk = (const float*)d_in[2];
  const float* wv = (const float*)d_in[3];
  const float* wo = (const float*)d_in[4];
  const float* qw = (const float*)d_in[5];
  const float* kw = (const float*)d_in[6];

  char* ws = (char*)d_ws;
  const size_t MB = 1 << 20;
  f16* xb     = (f16*)(ws + 0 * MB);    // 8 MB
  f16* wcat   = (f16*)(ws + 8 * MB);    // 6 MB  [3072][1024] = W^T for q|k|v
  f16* wot    = (f16*)(ws + 14 * MB);   // 2 MB  [1024][1024] = Wo^T
  f16* y      = (f16*)(ws + 16 * MB);   // 24 MB [4096][3072]
  f16* qatt   = (f16*)(ws + 40 * MB);   // 8 MB  [32][2048][64]
  f16* katt   = (f16*)(ws + 48 * MB);   // 8 MB
  f16* vatt   = (f16*)(ws + 56 * MB);   // 8 MB
  f16* vtb    = (f16*)(ws + 64 * MB);   // 8 MB  [32][64][2048]
  f16* attout = (f16*)(ws + 72 * MB);   // 8 MB  [4096][1024]

  k_cast_x<<<dim3(Mn * Dn / 4 / 256), 256, 0, stream>>>(x, xb);
  k_wtrans<<<dim3(16, 16, 4), 256, 0, stream>>>(wq, wk, wv, wo, wcat, wot);
  k_gemm<<<dim3(NQKV / 128, Mn / 128), 256, 0, stream>>>(xb, wcat, (void*)y, NQKV, Dn, 1);
  k_norm<<<dim3(Mn), 256, 0, stream>>>(y, qw, kw, qatt, katt, vatt);
  k_vtrans<<<dim3(Tn / 64, 32), 256, 0, stream>>>(vatt, vtb);
  k_attn<<<dim3(Tn / 64, 32), 256, 0, stream>>>(qatt, katt, vtb, attout);
  k_gemm<<<dim3(Dn / 128, Mn / 128), 256, 0, stream>>>(attout, wot, d_out, Dn, Dn, 0);
}

// Round 6
// 215.065 us; speedup vs baseline: 1.3327x; 1.1117x over previous
//
#include <hip/hip_runtime.h>

typedef _Float16 f16;
typedef _Float16 f16x8 __attribute__((ext_vector_type(8)));
typedef _Float16 f16x4 __attribute__((ext_vector_type(4)));
typedef float    f32x4 __attribute__((ext_vector_type(4)));

#define DEV __device__ __forceinline__

static constexpr int Tn = 2048;      // sequence length
static constexpr int Dn = 1024;      // model dim
static constexpr int Mn = 2 * Tn;    // 4096 rows (B*T)
static constexpr int NQKV = 3 * Dn;  // 3072

DEV void gld16(const void* g, void* l) {
  __builtin_amdgcn_global_load_lds((const __attribute__((address_space(1))) unsigned int*)g,
                                   (__attribute__((address_space(3))) unsigned int*)l, 16, 0, 0);
}

// packed f32->f16x2 convert + dword store (v_cvt_pkrtz_f16_f32 + ds_write_b32)
DEV void st_pk(void* p, float a, float b) {
  auto v = __builtin_amdgcn_cvt_pkrtz(a, b);
  *(unsigned int*)p = __builtin_bit_cast(unsigned int, v);
}

// ---------------- prep: cast x (f32->f16) + transpose/cast/permute weights ----------------
// blocks [0,4096): cast x. blocks [4096,5120): weight transpose, 64x64 tile each.
// For wq/wk/wv the destination row is permuted to head-contiguous: col c=d*16+h -> c'=h*64+d.
__global__ __launch_bounds__(256) void k_prep(const float* __restrict__ x, const float* __restrict__ wq,
                                              const float* __restrict__ wk, const float* __restrict__ wv,
                                              const float* __restrict__ wo, f16* __restrict__ xb,
                                              f16* __restrict__ wcat_t, f16* __restrict__ wot) {
  int bid = blockIdx.x;
  if (bid < 4096) {
    int i = bid * 256 + threadIdx.x;           // < Mn*Dn/4
    float4 v = ((const float4*)x)[i];
    f16x4 o4; o4.x = (f16)v.x; o4.y = (f16)v.y; o4.z = (f16)v.z; o4.w = (f16)v.w;
    ((f16x4*)xb)[i] = o4;
    return;
  }
  __shared__ float tile[64][65];
  int wb = bid - 4096;                          // 0..1023
  int z = wb >> 8;                              // 0..3 : wq,wk,wv,wo
  int rb = wb & 255;
  int k0 = (rb >> 4) * 64, n0 = (rb & 15) * 64;
  const float* srcs[4] = {wq, wk, wv, wo};
  const float* w = srcs[z];
  f16* dst = (z == 3) ? wot : wcat_t + (size_t)z * Dn * Dn;
#pragma unroll
  for (int p = 0; p < 16; ++p) {
    int flat = threadIdx.x + p * 256;
    int kl = flat >> 6, nl = flat & 63;
    tile[kl][nl] = w[(size_t)(k0 + kl) * Dn + n0 + nl];
  }
  __syncthreads();
#pragma unroll
  for (int p = 0; p < 16; ++p) {
    int flat = threadIdx.x + p * 256;
    int nl = flat >> 6, kl = flat & 63;
    int c = n0 + nl;
    int cp = (z == 3) ? c : (((c & 15) << 6) | (c >> 4));   // head-contiguous permute for q/k/v
    dst[(size_t)cp * Dn + k0 + kl] = (f16)tile[kl][nl];
  }
}

// ---------------- QKV GEMM (128x128 tile) with fused per-head RMSNorm epilogue ----------------
// A=xb [Mn][1024], Bt=wcat [3072][1024] (rows head-contiguous per section).
// Each wave's 64-col slice = exactly one head; q/k sections RMSNorm'd (q also gets
// 0.125*log2e fold), v copied. Outputs qatt/katt/vatt [32 bh][Tn][64] f16.
__global__ __launch_bounds__(256) void k_gemm_qkv(const f16* __restrict__ A, const f16* __restrict__ Bt,
                                                  const float* __restrict__ qw, const float* __restrict__ kw,
                                                  f16* __restrict__ qatt, f16* __restrict__ katt,
                                                  f16* __restrict__ vatt) {
  constexpr int K = 1024;
  __shared__ __align__(16) f16 As[128 * 64];
  __shared__ __align__(16) f16 Bs[128 * 64];
  const int lane = threadIdx.x & 63, wid = threadIdx.x >> 6;
  const int m0 = blockIdx.y * 128;
  const int n0 = blockIdx.x * 128;
  const int wr = (wid >> 1) * 64, wc = (wid & 1) * 64;
  f32x4 acc[4][4];
#pragma unroll
  for (int i = 0; i < 4; ++i)
#pragma unroll
    for (int j = 0; j < 4; ++j) acc[i][j] = (f32x4){0.f, 0.f, 0.f, 0.f};

  char* AsB = (char*)As; char* BsB = (char*)Bs;
  for (int k0 = 0; k0 < K; k0 += 64) {
    __syncthreads();
#pragma unroll
    for (int it = 0; it < 4; ++it) {
      int flat = ((wid * 4 + it) * 64 + lane) * 16;
      int row = flat >> 7, g = (flat >> 4) & 7;
      int sw = (g ^ (row & 7)) << 4;
      gld16((const char*)A + ((size_t)(m0 + row) * K + k0) * 2 + sw, AsB + (wid * 4 + it) * 1024);
      gld16((const char*)Bt + ((size_t)(n0 + row) * K + k0) * 2 + sw, BsB + (wid * 4 + it) * 1024);
    }
    __syncthreads();
#pragma unroll
    for (int kk = 0; kk < 2; ++kk) {
      f16x8 af[4], bf[4];
#pragma unroll
      for (int ms = 0; ms < 4; ++ms) {
        int r = wr + ms * 16 + (lane & 15);
        af[ms] = *(const f16x8*)(AsB + r * 128 + (((kk * 4 + (lane >> 4)) ^ (r & 7)) << 4));
      }
#pragma unroll
      for (int ns = 0; ns < 4; ++ns) {
        int r = wc + ns * 16 + (lane & 15);
        bf[ns] = *(const f16x8*)(BsB + r * 128 + (((kk * 4 + (lane >> 4)) ^ (r & 7)) << 4));
      }
#pragma unroll
      for (int ms = 0; ms < 4; ++ms)
#pragma unroll
        for (int ns = 0; ns < 4; ++ns)
          acc[ms][ns] = __builtin_amdgcn_mfma_f32_16x16x32_f16(af[ms], bf[ns], acc[ms][ns], 0, 0, 0);
    }
  }

  // fused epilogue: per (row, head) RMSNorm for q/k, pass-through for v
  const int rq = lane >> 4, cq = lane & 15;
  const int sec = blockIdx.x >> 3;                         // 0=q 1=k 2=v
  const int hwave = (((blockIdx.x & 7) * 128) + wc) >> 6;  // head 0..15
  f16* dst = (sec == 0) ? qatt : (sec == 1) ? katt : vatt;
  float wv[4];
#pragma unroll
  for (int ns = 0; ns < 4; ++ns) {
    if (sec == 0)      wv[ns] = qw[ns * 16 + cq] * 0.18033688011116013f;  // 0.125*log2(e)
    else if (sec == 1) wv[ns] = kw[ns * 16 + cq];
    else               wv[ns] = 1.f;
  }
#pragma unroll
  for (int ms = 0; ms < 4; ++ms) {
#pragma unroll
    for (int r = 0; r < 4; ++r) {
      int row = m0 + wr + ms * 16 + rq * 4 + r;
      float sc = 1.f;
      if (sec < 2) {
        float ss = 0.f;
#pragma unroll
        for (int ns = 0; ns < 4; ++ns) ss += acc[ms][ns][r] * acc[ms][ns][r];
        ss += __shfl_xor(ss, 1, 64);
        ss += __shfl_xor(ss, 2, 64);
        ss += __shfl_xor(ss, 4, 64);
        ss += __shfl_xor(ss, 8, 64);
        sc = rsqrtf(ss * (1.f / 64) + 1e-5f);
      }
      int b = row >> 11, t = row & 2047;
      size_t base = ((size_t)(b * 16 + hwave) * Tn + t) * 64;
#pragma unroll
      for (int ns = 0; ns < 4; ++ns)
        dst[base + ns * 16 + cq] = (f16)(acc[ms][ns][r] * sc * wv[ns]);
    }
  }
}

// ---------------- V transpose: vt[bh][d][t] = vatt[bh][t][d] ----------------
__global__ __launch_bounds__(256) void k_vtrans(const f16* __restrict__ vatt, f16* __restrict__ vt) {
  __shared__ f16 tile[64][72];
  int t0 = blockIdx.x * 64, bh = blockIdx.y;
  const f16* src = vatt + ((size_t)bh * Tn + t0) * 64;
#pragma unroll
  for (int p = 0; p < 2; ++p) {
    int c = threadIdx.x + p * 256;     // 0..511
    int tl = c >> 3, dc = (c & 7) * 8;
    f16x8 v = *(const f16x8*)(src + (size_t)tl * 64 + dc);
#pragma unroll
    for (int j = 0; j < 8; ++j) tile[dc + j][tl] = v[j];
  }
  __syncthreads();
#pragma unroll
  for (int p = 0; p < 2; ++p) {
    int c = threadIdx.x + p * 256;
    int d = c >> 3, tc = (c & 7) * 8;
    f16x8 o;
#pragma unroll
    for (int j = 0; j < 8; ++j) o[j] = tile[d][tc + j];
    *(f16x8*)(vt + ((size_t)bh * 64 + d) * Tn + t0 + tc) = o;
  }
}

// ---------------- flash attention: 4 waves x 16 q-rows, KVBLK=64 ----------------
// Swapped QK^T (mfma(K,Q)) puts a full P-row per lane (q=lane&15).
// No-max softmax (|S_log2| <= 11.55 by Cauchy-Schwarz after RMSNorm); P=exp2(S) via
// cvt_pkrtz-packed dword stores to a wave-private swizzled LDS row-buffer, read back
// as the PV A-fragment with 2 ds_read_b128. Row-sum deferred entirely to epilogue.
// P-write offset: element k=sub*16+g*4+r -> chunk sub*2+(g>>1) (XOR'd with q&7),
// within-chunk byte (g&1)*8 + 2r.  (R4's bug: g*8 added outside the XOR -> overflow.)
__global__ __launch_bounds__(256) void k_attn(const f16* __restrict__ qatt, const f16* __restrict__ katt,
                                              const f16* __restrict__ vt, f16* __restrict__ attout) {
  __shared__ __align__(16) f16 Ks[2][64 * 64];
  __shared__ __align__(16) f16 Vs[2][64 * 64];
  __shared__ __align__(16) f16 Ps[4][1024];     // 2KB per wave: 16 rows x 128B, XOR-swizzled
  const int lane = threadIdx.x & 63, wid = threadIdx.x >> 6;
  const int q = lane & 15, g = lane >> 4;
  const int bh = blockIdx.y, b = bh >> 4, h = bh & 15;
  const int tq0 = blockIdx.x * 64 + wid * 16;

  const f16* qbase = qatt + ((size_t)bh * Tn + tq0) * 64;
  f16x8 qf[2];
#pragma unroll
  for (int kk = 0; kk < 2; ++kk)
    qf[kk] = *(const f16x8*)(qbase + (size_t)q * 64 + kk * 32 + g * 8);

  f32x4 o[4];
#pragma unroll
  for (int i = 0; i < 4; ++i) o[i] = (f32x4){0.f, 0.f, 0.f, 0.f};
  float psum = 0.f;

  const char* kgb = (const char*)(katt + (size_t)bh * Tn * 64);
  const char* vgb = (const char*)(vt + (size_t)bh * 64 * Tn);
  char* KsB = (char*)Ks; char* VsB = (char*)Vs;
  char* PsB = (char*)Ps + wid * 2048;
  const int xq = (q & 7) << 4;
  // P-write pointers (loop-invariant): chunk (sub*2+(g>>1))^(q&7), within (g&1)*8
  char* pwr[4];
#pragma unroll
  for (int sub = 0; sub < 4; ++sub)
    pwr[sub] = PsB + q * 128 + ((g & 1) * 8) + ((((sub * 2) + (g >> 1)) ^ (q & 7)) << 4);
  const char* prd0 = PsB + q * 128 + ((g * 16) ^ xq);       // PV A-frag kk=0 (chunk g)
  const char* prd1 = PsB + q * 128 + (((64 + g * 16)) ^ xq);// PV A-frag kk=1 (chunk 4+g)

  auto stage = [&](int buf, int kt) {
    int k0 = kt * 64;
#pragma unroll
    for (int it = 0; it < 2; ++it) {
      int flat = ((wid * 2 + it) * 64 + lane) * 16;
      int row = flat >> 7, gg = (flat >> 4) & 7;
      int sw = (gg ^ (row & 7)) << 4;
      gld16(kgb + ((size_t)(k0 + row) * 64) * 2 + sw, KsB + buf * 8192 + (wid * 2 + it) * 1024);
      gld16(vgb + ((size_t)row * Tn + k0) * 2 + sw, VsB + buf * 8192 + (wid * 2 + it) * 1024);
    }
  };

  constexpr int NT = Tn / 64;
  stage(0, 0);

  for (int kt = 0; kt < NT; ++kt) {
    const int cur = kt & 1;
    const char* Kc = KsB + cur * 8192;
    const char* Vc = VsB + cur * 8192;
    if (kt + 1 < NT) {
      stage(cur ^ 1, kt + 1);
      asm volatile("s_waitcnt vmcnt(4)" ::: "memory");
    } else {
      asm volatile("s_waitcnt vmcnt(0)" ::: "memory");
    }
    __builtin_amdgcn_s_barrier();
    __builtin_amdgcn_sched_barrier(0);

    // S^T = K Q : lane holds S[k = sub*16+g*4+r][q]
    f32x4 s[4];
    __builtin_amdgcn_s_setprio(1);
#pragma unroll
    for (int sub = 0; sub < 4; ++sub) {
      s[sub] = (f32x4){0.f, 0.f, 0.f, 0.f};
#pragma unroll
      for (int kk = 0; kk < 2; ++kk) {
        int kr = sub * 16 + q;
        f16x8 kf = *(const f16x8*)(Kc + kr * 128 + (((kk * 4 + g) ^ (kr & 7)) << 4));
        s[sub] = __builtin_amdgcn_mfma_f32_16x16x32_f16(kf, qf[kk], s[sub], 0, 0, 0);
      }
    }
    __builtin_amdgcn_s_setprio(0);

    // P = exp2(S): packed f16x2 dword stores (loop-invariant addresses)
#pragma unroll
    for (int sub = 0; sub < 2; ++sub) {
      float e0 = __builtin_amdgcn_exp2f(s[sub][0]);
      float e1 = __builtin_amdgcn_exp2f(s[sub][1]);
      float e2 = __builtin_amdgcn_exp2f(s[sub][2]);
      float e3 = __builtin_amdgcn_exp2f(s[sub][3]);
      psum += (e0 + e1) + (e2 + e3);
      st_pk(pwr[sub],     e0, e1);
      st_pk(pwr[sub] + 4, e2, e3);
    }
    f16x8 pa0 = *(const f16x8*)prd0;
#pragma unroll
    for (int sub = 2; sub < 4; ++sub) {
      float e0 = __builtin_amdgcn_exp2f(s[sub][0]);
      float e1 = __builtin_amdgcn_exp2f(s[sub][1]);
      float e2 = __builtin_amdgcn_exp2f(s[sub][2]);
      float e3 = __builtin_amdgcn_exp2f(s[sub][3]);
      psum += (e0 + e1) + (e2 + e3);
      st_pk(pwr[sub],     e0, e1);
      st_pk(pwr[sub] + 4, e2, e3);
    }
    f16x8 pa1 = *(const f16x8*)prd1;

    // O += P V
    __builtin_amdgcn_s_setprio(1);
#pragma unroll
    for (int ds = 0; ds < 4; ++ds) {
      int dr = ds * 16 + q;
      f16x8 vb0 = *(const f16x8*)(Vc + dr * 128 + (((0 + g) ^ (dr & 7)) << 4));
      o[ds] = __builtin_amdgcn_mfma_f32_16x16x32_f16(pa0, vb0, o[ds], 0, 0, 0);
      f16x8 vb1 = *(const f16x8*)(Vc + dr * 128 + (((4 + g) ^ (dr & 7)) << 4));
      o[ds] = __builtin_amdgcn_mfma_f32_16x16x32_f16(pa1, vb1, o[ds], 0, 0, 0);
    }
    __builtin_amdgcn_s_setprio(0);
    __builtin_amdgcn_s_barrier();   // all waves done reading buf[cur] before restage
  }

  // epilogue: total row-sum (lanes q, q+16, q+32, q+48), broadcast 1/sum to O rows
  psum += __shfl_xor(psum, 16, 64);
  psum += __shfl_xor(psum, 32, 64);
  float invq = 1.f / psum;            // valid on every lane, for row q=lane&15
  float inv[4];
#pragma unroll
  for (int r = 0; r < 4; ++r)
    inv[r] = __int_as_float(__builtin_amdgcn_ds_bpermute(((g * 4 + r)) << 2, __float_as_int(invq)));
#pragma unroll
  for (int ds = 0; ds < 4; ++ds)
#pragma unroll
    for (int r = 0; r < 4; ++r) {
      int t = tq0 + g * 4 + r;
      attout[((size_t)(b * Tn + t)) * Dn + h * 64 + ds * 16 + q] = (f16)(o[ds][r] * inv[r]);
    }
}

// ---------------- out-proj GEMM: 64x128 tile (2 blocks/CU for occupancy) ----------------
__global__ __launch_bounds__(256) void k_gemm_o(const f16* __restrict__ A, const f16* __restrict__ Bt,
                                                float* __restrict__ C, int N, int K) {
  __shared__ __align__(16) f16 As[64 * 64];
  __shared__ __align__(16) f16 Bs[128 * 64];
  const int lane = threadIdx.x & 63, wid = threadIdx.x >> 6;
  const int m0 = blockIdx.y * 64, n0 = blockIdx.x * 128;
  const int wr = (wid >> 1) * 32, wc = (wid & 1) * 64;
  f32x4 acc[2][4];
#pragma unroll
  for (int i = 0; i < 2; ++i)
#pragma unroll
    for (int j = 0; j < 4; ++j) acc[i][j] = (f32x4){0.f, 0.f, 0.f, 0.f};

  char* AsB = (char*)As; char* BsB = (char*)Bs;
  for (int k0 = 0; k0 < K; k0 += 64) {
    __syncthreads();
#pragma unroll
    for (int it = 0; it < 2; ++it) {
      int flat = ((wid * 2 + it) * 64 + lane) * 16;
      int row = flat >> 7, g = (flat >> 4) & 7;
      int sw = (g ^ (row & 7)) << 4;
      gld16((const char*)A + ((size_t)(m0 + row) * K + k0) * 2 + sw, AsB + (wid * 2 + it) * 1024);
    }
#pragma unroll
    for (int it = 0; it < 4; ++it) {
      int flat = ((wid * 4 + it) * 64 + lane) * 16;
      int row = flat >> 7, g = (flat >> 4) & 7;
      int sw = (g ^ (row & 7)) << 4;
      gld16((const char*)Bt + ((size_t)(n0 + row) * K + k0) * 2 + sw, BsB + (wid * 4 + it) * 1024);
    }
    __syncthreads();
#pragma unroll
    for (int kk = 0; kk < 2; ++kk) {
      f16x8 af[2], bf[4];
#pragma unroll
      for (int ms = 0; ms < 2; ++ms) {
        int r = wr + ms * 16 + (lane & 15);
        af[ms] = *(const f16x8*)(AsB + r * 128 + (((kk * 4 + (lane >> 4)) ^ (r & 7)) << 4));
      }
#pragma unroll
      for (int ns = 0; ns < 4; ++ns) {
        int r = wc + ns * 16 + (lane & 15);
        bf[ns] = *(const f16x8*)(BsB + r * 128 + (((kk * 4 + (lane >> 4)) ^ (r & 7)) << 4));
      }
#pragma unroll
      for (int ms = 0; ms < 2; ++ms)
#pragma unroll
        for (int ns = 0; ns < 4; ++ns)
          acc[ms][ns] = __builtin_amdgcn_mfma_f32_16x16x32_f16(af[ms], bf[ns], acc[ms][ns], 0, 0, 0);
    }
  }
  const int rq = lane >> 4, cq = lane & 15;
#pragma unroll
  for (int ms = 0; ms < 2; ++ms)
#pragma unroll
    for (int ns = 0; ns < 4; ++ns)
#pragma unroll
      for (int r = 0; r < 4; ++r)
        C[(size_t)(m0 + wr + ms * 16 + rq * 4 + r) * N + n0 + wc + ns * 16 + cq] = acc[ms][ns][r];
}

// ---------------- host launch ----------------
extern "C" void kernel_launch(void* const* d_in, const int* in_sizes, int n_in,
                              void* d_out, int out_size, void* d_ws, size_t ws_size,
                              hipStream_t stream) {
  const float* x  = (const float*)d_in[0];
  const float* wq = (const float*)d_in[1];
  const float* wk = (const float*)d_in[2];
  const float* wv = (const float*)d_in[3];
  const float* wo = (const float*)d_in[4];
  const float* qw = (const float*)d_in[5];
  const float* kw = (const float*)d_in[6];

  char* ws = (char*)d_ws;
  const size_t MB = 1 << 20;
  f16* xb     = (f16*)(ws + 0 * MB);    // 8 MB
  f16* wcat   = (f16*)(ws + 8 * MB);    // 6 MB  [3072][1024] head-contiguous rows
  f16* wot    = (f16*)(ws + 14 * MB);   // 2 MB  [1024][1024] = Wo^T
  f16* qatt   = (f16*)(ws + 16 * MB);   // 8 MB  [32][2048][64]
  f16* katt   = (f16*)(ws + 24 * MB);   // 8 MB
  f16* vatt   = (f16*)(ws + 32 * MB);   // 8 MB
  f16* vtb    = (f16*)(ws + 40 * MB);   // 8 MB  [32][64][2048]
  f16* attout = (f16*)(ws + 48 * MB);   // 8 MB  [4096][1024]

  k_prep<<<dim3(5120), 256, 0, stream>>>(x, wq, wk, wv, wo, xb, wcat, wot);
  k_gemm_qkv<<<dim3(NQKV / 128, Mn / 128), 256, 0, stream>>>(xb, wcat, qw, kw, qatt, katt, vatt);
  k_vtrans<<<dim3(Tn / 64, 32), 256, 0, stream>>>(vatt, vtb);
  k_attn<<<dim3(Tn / 64, 32), 256, 0, stream>>>(qatt, katt, vtb, attout);
  k_gemm_o<<<dim3(Dn / 128, Mn / 64), 256, 0, stream>>>(attout, wot, (float*)d_out, Dn, Dn);
}